// Round 6
// baseline (753.667 us; speedup 1.0000x reference)
//
#include <hip/hip_runtime.h>

#define NB 65536

typedef unsigned long long u64;
typedef __attribute__((ext_vector_type(8))) short short8;   // 8 bf16
typedef __attribute__((ext_vector_type(4))) float f32x4;

union FragAB { unsigned short us[8]; unsigned w[4]; short8 v; };

__device__ __forceinline__ float sigf(float x){ return 1.0f/(1.0f + __expf(-x)); }
__device__ __forceinline__ float tanh_fast(float x){ return 1.0f - 2.0f/(1.0f + __expf(2.0f*x)); }

__device__ __forceinline__ unsigned short f2bf(float f){
    union { float f; unsigned u; } x; x.f = f;
    unsigned r = x.u + 0x7FFFu + ((x.u >> 16) & 1u);   // RNE
    return (unsigned short)(r >> 16);
}
__device__ __forceinline__ float bf2f(unsigned short h){
    union { unsigned u; float f; } x; x.u = ((unsigned)h) << 16; return x.f;
}

// ============ Kernel 1: conv+LIF, phase-parallel within block ============
// Block = 256 threads, 16 samples. Phase 1 (conv): thread (sm=tid&15, pg=tid>>4),
// pg 0..14 computes positions 6pg..6pg+5 -> hv fp32 in LDS [site][17-padded].
// Phase 2 (LIF): thread (sm, kg) scans chains kk=2kg,2kg+1 (+32 for kg15);
// 32-bit spike timelines in registers. Phase 3: transpose timelines -> packed
// u64 spike words per t, plus avg reduce. fp32 LIF = bit-faithful thresholds.
__global__ __launch_bounds__(256)
void k_conv_lif(const float* __restrict__ x,
                const float* __restrict__ c1w, const float* __restrict__ c1b,
                const float* __restrict__ b1g, const float* __restrict__ b1b,
                const float* __restrict__ b1m, const float* __restrict__ b1v,
                const float* __restrict__ c2w, const float* __restrict__ c2b,
                const float* __restrict__ b2g, const float* __restrict__ b2b,
                const float* __restrict__ b2m, const float* __restrict__ b2v,
                u64* __restrict__ spk,
                float* __restrict__ avg)
{
    __shared__ float    hv[1056][17];   // 71.8 KB, pad 17 breaks bank alignment
    __shared__ unsigned tml[33][16];    // per-chain 32-bit spike timelines
    __shared__ float    wavg[4][12][16];

    const int tid  = threadIdx.x;
    const int sm   = tid & 15;
    const int pg   = tid >> 4;          // 0..15
    const int lane = tid & 63;
    const int wv   = tid >> 6;          // 0..3
    const int bidx = blockIdx.x * 16 + sm;
    const float* xr = x + (size_t)bidx * 360;

    // fold conv1 bias + bn1
    float w1f[6][5], c1f[6];
    #pragma unroll
    for (int c = 0; c < 6; ++c) {
        float s = b1g[c] / sqrtf(b1v[c] + 1e-5f);
        #pragma unroll
        for (int j = 0; j < 5; ++j) w1f[c][j] = c1w[c*5+j] * s;
        c1f[c] = (c1b[c] - b1m[c]) * s + b1b[c];
    }
    float s2v[12], t2v[12], sum12[12];
    #pragma unroll
    for (int c = 0; c < 12; ++c) {
        float s = b2g[c] / sqrtf(b2v[c] + 1e-5f);
        s2v[c] = s;
        t2v[c] = (c2b[c] - b2m[c]) * s + b2b[c];
        sum12[c] = 0.f;
    }

    // ---- phase 1: conv ----
    if (pg < 15) {
        const int p0 = 6*pg;
        float xw[32];
        #pragma unroll
        for (int e = 0; e < 8; ++e) {
            const int gi = 24*pg - 4 + 4*e;
            float4 v;
            if (gi >= 0 && gi <= 356) v = *(const float4*)(xr + gi);
            else                      v = make_float4(0.f,0.f,0.f,0.f);
            xw[4*e+0]=v.x; xw[4*e+1]=v.y; xw[4*e+2]=v.z; xw[4*e+3]=v.w;
        }
        float hA[6], hB[6], hC[6];
        {
            const bool valid = (pg > 0);   // h1 col 2p0-1; col -1 is pad
            #pragma unroll
            for (int c = 0; c < 6; ++c) {
                float a = c1f[c] + w1f[c][0]*xw[0] + w1f[c][1]*xw[1]
                        + w1f[c][2]*xw[2] + w1f[c][3]*xw[3] + w1f[c][4]*xw[4];
                hA[c] = valid ? fmaxf(a, 0.f) : 0.f;
            }
        }
        #pragma unroll
        for (int i = 0; i < 6; ++i) {
            const float xv0 = xw[4*i+2], xv1 = xw[4*i+3], xv2 = xw[4*i+4],
                        xv3 = xw[4*i+5], xv4 = xw[4*i+6], xv5 = xw[4*i+7],
                        xv6 = xw[4*i+8];
            #pragma unroll
            for (int c = 0; c < 6; ++c) {
                float aB = c1f[c] + w1f[c][0]*xv0 + w1f[c][1]*xv1 + w1f[c][2]*xv2
                                  + w1f[c][3]*xv3 + w1f[c][4]*xv4;
                float aC = c1f[c] + w1f[c][0]*xv2 + w1f[c][1]*xv3 + w1f[c][2]*xv4
                                  + w1f[c][3]*xv5 + w1f[c][4]*xv6;
                hB[c] = fmaxf(aB, 0.f);
                hC[c] = fmaxf(aC, 0.f);
            }
            #pragma unroll
            for (int c2 = 0; c2 < 12; ++c2) {
                float acc = 0.f;
                #pragma unroll
                for (int c1 = 0; c1 < 6; ++c1) {
                    const float* wp = c2w + c2*18 + c1*3;
                    acc += wp[0]*hA[c1] + wp[1]*hB[c1] + wp[2]*hC[c1];
                }
                float hvv = fmaxf(acc*s2v[c2] + t2v[c2], 0.f);
                sum12[c2] += hvv;
                const int site = 72*pg + 12*i + c2;
                if (site < 1056) hv[site][sm] = hvv;
            }
            #pragma unroll
            for (int c = 0; c < 6; ++c) hA[c] = hC[c];
        }
    }
    // reduce sum12 across the 4 pg-groups of this wave (lanes with same sm)
    #pragma unroll
    for (int c = 0; c < 12; ++c) {
        float v = sum12[c];
        v += __shfl_xor(v, 16);
        v += __shfl_xor(v, 32);
        sum12[c] = v;
    }
    if (lane < 16) {
        #pragma unroll
        for (int c = 0; c < 12; ++c) wavg[wv][c][sm] = sum12[c];
    }
    __syncthreads();

    // ---- phase 2: LIF scan, chains kk = 2kg, 2kg+1 (+32 for kg==15) ----
    {
        const int kg  = pg;
        const int kka = 2*kg, kkb = 2*kg + 1;
        const bool hc = (kg == 15);
        float m1a=0.f,m2a=0.f,m1b=0.f,m2b=0.f,m1c=0.f,m2c=0.f;
        unsigned ba=0u, bb=0u, bc=0u;
        #pragma unroll
        for (int t = 0; t < 32; ++t) {
            const float va = hv[33*t + kka][sm];
            const float vb = hv[33*t + kkb][sm];
            const float vc = hc ? hv[33*t + 32][sm] : 0.f;
            { m1a = 0.95f*m1a + va; float s1 = (m1a>0.5f)?1.f:0.f; m1a *= (1.f-s1);
              float v2 = 0.9f*m2a + s1; bool s2 = (v2>0.6f); m2a = s2?0.f:v2;
              if (s2) ba |= (1u<<t); }
            { m1b = 0.95f*m1b + vb; float s1 = (m1b>0.5f)?1.f:0.f; m1b *= (1.f-s1);
              float v2 = 0.9f*m2b + s1; bool s2 = (v2>0.6f); m2b = s2?0.f:v2;
              if (s2) bb |= (1u<<t); }
            { m1c = 0.95f*m1c + vc; float s1 = (m1c>0.5f)?1.f:0.f; m1c *= (1.f-s1);
              float v2 = 0.9f*m2c + s1; bool s2 = (v2>0.6f); m2c = s2?0.f:v2;
              if (s2) bc |= (1u<<t); }
        }
        tml[kka][sm] = ba;
        tml[kkb][sm] = bb;
        if (hc) tml[32][sm] = bc;
    }
    __syncthreads();

    // ---- phase 3: transpose timelines -> spk words; combine avg ----
    {
        const int tg = pg;                 // t = 2tg, 2tg+1
        u64 w0 = 0ull, w1 = 0ull;
        #pragma unroll
        for (int kk = 0; kk < 33; ++kk) {
            const unsigned r = tml[kk][sm];
            w0 |= (u64)((r >> (2*tg  )) & 1u) << kk;
            w1 |= (u64)((r >> (2*tg+1)) & 1u) << kk;
        }
        spk[(size_t)(2*tg  )*NB + bidx] = w0;
        spk[(size_t)(2*tg+1)*NB + bidx] = w1;
    }
    if (tid < 192) {
        const int c2 = tid >> 4;
        float s = wavg[0][c2][sm] + wavg[1][c2][sm] + wavg[2][c2][sm] + wavg[3][c2][sm];
        avg[(size_t)c2*NB + bidx] = s / 90.0f;
    }
}

// ============ Kernel 2: MFMA LSTM (split-bf16) + heads ============
// Single-wave block (64 threads): no launch_bounds VGPR squeeze -> weight
// fragments stay register-resident (24 frags = 96 VGPRs). k=32 spike input
// folded into WhhHi A-slot k=24; q==3 lanes patch B elem 0 in-register.
__global__ __launch_bounds__(64)
void k_lstm_mfma(const u64* __restrict__ spk,
                 const float* __restrict__ avg,
                 const float* __restrict__ wih, const float* __restrict__ whh,
                 const float* __restrict__ bih, const float* __restrict__ bhh,
                 const float* __restrict__ rw1, const float* __restrict__ rb1,
                 const float* __restrict__ rw2, const float* __restrict__ rb2,
                 const float* __restrict__ fw,  const float* __restrict__ fb,
                 const float* __restrict__ cw1, const float* __restrict__ cb1,
                 const float* __restrict__ cw2, const float* __restrict__ cb2,
                 float* __restrict__ out)
{
    __shared__ unsigned short hx[16][64];  // [n][0..23]=h_hi, [32..55]=h_lo, rest 0
    __shared__ float hf[16][24];

    const int lane = threadIdx.x & 63;
    const int q    = lane >> 4;
    const int n16  = lane & 15;
    const int sample = blockIdx.x * 16 + n16;

    {   // zero hx: 512 dwords / 64 lanes = 8 each
        unsigned* zp = (unsigned*)&hx[0][0];
        #pragma unroll
        for (int i = 0; i < 8; ++i) zp[lane + 64*i] = 0u;
    }

    // ---- A fragments (one-time): Wih hi/lo (k=0..31), Whh hi/lo (k=0..23, k24=wih[32]) ----
    short8 WihHi[6], WihLo[6], WhhHi[6], WhhLo[6];
    #pragma unroll
    for (int m = 0; m < 6; ++m) {
        const int rowA = 16*m + n16;
        const int u    = rowA >> 2;
        const int gt   = rowA & 3;
        const float* wr = wih + (gt*24 + u)*33;
        FragAB fh, fl;
        #pragma unroll
        for (int j = 0; j < 8; ++j) {
            float v = wr[q*8 + j];
            unsigned short h = f2bf(v);
            fh.us[j] = h;
            fl.us[j] = f2bf(v - bf2f(h));
        }
        WihHi[m] = fh.v; WihLo[m] = fl.v;

        const float* hr = whh + (gt*24 + u)*24;
        FragAB gh, gl;
        #pragma unroll
        for (int j = 0; j < 8; ++j) {
            const int k = q*8 + j;
            float v = (k < 24) ? hr[k] : ((k == 24) ? wr[32] : 0.f);
            unsigned short h = f2bf(v);
            gh.us[j] = h;
            gl.us[j] = (k < 24) ? f2bf(v - bf2f(h)) : (unsigned short)0;
        }
        WhhHi[m] = gh.v; WhhLo[m] = gl.v;
    }

    float bias[6][4];
    #pragma unroll
    for (int m = 0; m < 6; ++m) {
        const int u = 4*m + q;
        #pragma unroll
        for (int rr = 0; rr < 4; ++rr)
            bias[m][rr] = bih[rr*24 + u] + bhh[rr*24 + u];
    }

    float cst[6], hreg[6];
    #pragma unroll
    for (int m = 0; m < 6; ++m) { cst[m] = 0.f; hreg[m] = 0.f; }

    const u64* sp = spk + sample;
    u64 wcur = sp[0];
    const int q8 = q * 8;

    __asm__ volatile("s_waitcnt lgkmcnt(0)" ::: "memory");

    #pragma unroll 1
    for (int t = 0; t < 32; ++t) {
        FragAB bhHi, bhLo;
        bhHi.v = *reinterpret_cast<const short8*>(&hx[n16][q8]);
        bhLo.v = *reinterpret_cast<const short8*>(&hx[n16][32 + q8]);

        const unsigned lo32 = (unsigned)wcur;
        const unsigned hi32 = (unsigned)(wcur >> 32);
        // patch B slot k=24 (q==3, j==0) with spike bit 32 (exact bf16 0/1)
        if (q == 3) bhHi.us[0] = (hi32 & 1u) ? (unsigned short)0x3F80 : (unsigned short)0;

        FragAB bs0;
        {
            const unsigned byt = (lo32 >> q8) & 0xFFu;
            #pragma unroll
            for (int p = 0; p < 4; ++p) {
                unsigned e0 = (byt >> (2*p)) & 1u;
                unsigned e1 = (byt >> (2*p+1)) & 1u;
                bs0.w[p] = (e0 ? 0x3F80u : 0u) | (e1 ? 0x3F800000u : 0u);
            }
        }

        u64 wnext = 0;
        if (t < 31) wnext = sp[(size_t)(t+1)*NB];

        f32x4 acc[6];
        #pragma unroll
        for (int m = 0; m < 6; ++m) {
            f32x4 a; a[0]=bias[m][0]; a[1]=bias[m][1]; a[2]=bias[m][2]; a[3]=bias[m][3];
            a = __builtin_amdgcn_mfma_f32_16x16x32_bf16(WihHi[m], bs0.v,  a, 0, 0, 0);
            a = __builtin_amdgcn_mfma_f32_16x16x32_bf16(WihLo[m], bs0.v,  a, 0, 0, 0);
            a = __builtin_amdgcn_mfma_f32_16x16x32_bf16(WhhHi[m], bhHi.v, a, 0, 0, 0);
            a = __builtin_amdgcn_mfma_f32_16x16x32_bf16(WhhLo[m], bhHi.v, a, 0, 0, 0);
            a = __builtin_amdgcn_mfma_f32_16x16x32_bf16(WhhHi[m], bhLo.v, a, 0, 0, 0);
            acc[m] = a;
        }

        #pragma unroll
        for (int m = 0; m < 6; ++m) {
            float ii = sigf(acc[m][0]);
            float ff = sigf(acc[m][1]);
            float gg = tanh_fast(acc[m][2]);
            float oo = sigf(acc[m][3]);
            float cn = ff*cst[m] + ii*gg;
            cst[m] = cn;
            float h = oo * tanh_fast(cn);
            hreg[m] = h;
            unsigned short hh = f2bf(h);
            unsigned short hl = f2bf(h - bf2f(hh));
            hx[n16][4*m + q]      = hh;
            hx[n16][32 + 4*m + q] = hl;
        }
        __asm__ volatile("s_waitcnt lgkmcnt(0)" ::: "memory");
        wcur = wnext;
    }

    #pragma unroll
    for (int m = 0; m < 6; ++m) hf[n16][4*m + q] = hreg[m];
    __asm__ volatile("s_waitcnt lgkmcnt(0)" ::: "memory");

    if (lane < 16) {
        const int sm = lane;
        const int bidx = blockIdx.x * 16 + sm;
        float h[24];
        #pragma unroll
        for (int u2 = 0; u2 < 24; ++u2) h[u2] = hf[sm][u2];
        float av[12];
        #pragma unroll
        for (int cc = 0; cc < 12; ++cc) av[cc] = avg[(size_t)cc*NB + bidx];

        float f1[12];
        #pragma unroll
        for (int r = 0; r < 12; ++r) {
            float a = rb1[r];
            #pragma unroll
            for (int u2 = 0; u2 < 24; ++u2) a += rw1[r*36+u2]*h[u2];
            #pragma unroll
            for (int cc = 0; cc < 12; ++cc) a += rw1[r*36+24+cc]*av[cc];
            f1[r] = fmaxf(a, 0.f);
        }
        float z0 = rb2[0], z1 = rb2[1];
        #pragma unroll
        for (int r = 0; r < 12; ++r) { z0 += rw2[r]*f1[r]; z1 += rw2[12+r]*f1[r]; }
        float mz = fmaxf(z0, z1);
        float e0 = __expf(z0 - mz), e1 = __expf(z1 - mz);
        float inv = 1.0f/(e0 + e1);
        float r0 = 0.7f*e0*inv, r1 = 0.3f*e1*inv;
        float alpha = r0/(r0 + r1);

        float ha[24], sa[12];
        #pragma unroll
        for (int u2 = 0; u2 < 24; ++u2) ha[u2] = h[u2]*alpha;
        #pragma unroll
        for (int cc = 0; cc < 12; ++cc) sa[cc] = av[cc]*(1.f - alpha);

        float fu[24];
        #pragma unroll
        for (int r = 0; r < 24; ++r) {
            float a = fb[r];
            #pragma unroll
            for (int u2 = 0; u2 < 24; ++u2) a += fw[r*36+u2]*ha[u2];
            #pragma unroll
            for (int cc = 0; cc < 12; ++cc) a += fw[r*36+24+cc]*sa[cc];
            fu[r] = fmaxf(a, 0.f);
        }
        float c1o[12];
        #pragma unroll
        for (int r = 0; r < 12; ++r) {
            float a = cb1[r];
            #pragma unroll
            for (int u2 = 0; u2 < 24; ++u2) a += cw1[r*24+u2]*fu[u2];
            c1o[r] = fmaxf(a, 0.f);
        }
        #pragma unroll
        for (int o = 0; o < 5; ++o) {
            float a = cb2[o];
            #pragma unroll
            for (int r = 0; r < 12; ++r) a += cw2[o*12+r]*c1o[r];
            out[(size_t)bidx*5 + o] = a;
        }
    }
}

extern "C" void kernel_launch(void* const* d_in, const int* in_sizes, int n_in,
                              void* d_out, int out_size, void* d_ws, size_t ws_size,
                              hipStream_t stream) {
    const float* x    = (const float*)d_in[0];
    const float* c1w  = (const float*)d_in[1];
    const float* c1b  = (const float*)d_in[2];
    const float* b1g  = (const float*)d_in[3];
    const float* b1b  = (const float*)d_in[4];
    const float* b1m  = (const float*)d_in[5];
    const float* b1v  = (const float*)d_in[6];
    const float* c2w  = (const float*)d_in[7];
    const float* c2b  = (const float*)d_in[8];
    const float* b2g  = (const float*)d_in[9];
    const float* b2b  = (const float*)d_in[10];
    const float* b2m  = (const float*)d_in[11];
    const float* b2v  = (const float*)d_in[12];
    const float* wih  = (const float*)d_in[13];
    const float* whh  = (const float*)d_in[14];
    const float* bih  = (const float*)d_in[15];
    const float* bhh  = (const float*)d_in[16];
    const float* rw1  = (const float*)d_in[17];
    const float* rb1  = (const float*)d_in[18];
    const float* rw2  = (const float*)d_in[19];
    const float* rb2  = (const float*)d_in[20];
    const float* fw   = (const float*)d_in[21];
    const float* fb   = (const float*)d_in[22];
    const float* cw1  = (const float*)d_in[23];
    const float* cb1  = (const float*)d_in[24];
    const float* cw2  = (const float*)d_in[25];
    const float* cb2  = (const float*)d_in[26];
    float* out = (float*)d_out;

    u64* spk  = (u64*)d_ws;                                            // 16.78 MB
    float* avg = (float*)((char*)d_ws + (size_t)32*NB*sizeof(u64));    // 3.15 MB

    k_conv_lif<<<dim3(NB/16), dim3(256), 0, stream>>>(x, c1w, c1b, b1g, b1b, b1m, b1v,
                                                      c2w, c2b, b2g, b2b, b2m, b2v, spk, avg);
    k_lstm_mfma<<<dim3(NB/16), dim3(64), 0, stream>>>(spk, avg, wih, whh, bih, bhh,
                                                      rw1, rb1, rw2, rb2, fw, fb,
                                                      cw1, cb1, cw2, cb2, out);
}

// Round 7
// 521.109 us; speedup vs baseline: 1.4463x; 1.4463x over previous
//
#include <hip/hip_runtime.h>

#define NB 65536

typedef unsigned long long u64;
typedef __attribute__((ext_vector_type(8))) short short8;   // 8 bf16
typedef __attribute__((ext_vector_type(4))) float f32x4;

union FragAB { unsigned short us[8]; unsigned w[4]; short8 v; };
union WU     { uint4 u4; short8 v; };

__device__ __forceinline__ float sigf(float x){ return 1.0f/(1.0f + __expf(-x)); }
__device__ __forceinline__ float tanh_fast(float x){ return 1.0f - 2.0f/(1.0f + __expf(2.0f*x)); }

__device__ __forceinline__ unsigned short f2bf(float f){
    union { float f; unsigned u; } x; x.f = f;
    unsigned r = x.u + 0x7FFFu + ((x.u >> 16) & 1u);   // RNE
    return (unsigned short)(r >> 16);
}
__device__ __forceinline__ float bf2f(unsigned short h){
    union { unsigned u; float f; } x; x.u = ((unsigned)h) << 16; return x.f;
}

// ============ Kernel 0: one-time weight prep for the MFMA LSTM ============
// 64 lanes; lane layout matches the LSTM kernel exactly, so the LSTM preamble
// is 24 coalesced dwordx4 loads instead of ~150 gathers + f2bf ALU chains.
__global__ __launch_bounds__(64)
void k_setup(const float* __restrict__ wih, const float* __restrict__ whh,
             const float* __restrict__ bih, const float* __restrict__ bhh,
             uint4* __restrict__ wtab, float4* __restrict__ btab)
{
    const int lane = threadIdx.x;
    const int q    = lane >> 4;
    const int n16  = lane & 15;
    #pragma unroll
    for (int m = 0; m < 6; ++m) {
        const int rowA = 16*m + n16;
        const int u    = rowA >> 2;
        const int gt   = rowA & 3;
        const float* wr = wih + (gt*24 + u)*33;
        FragAB fh, fl;
        #pragma unroll
        for (int j = 0; j < 8; ++j) {
            float v = wr[q*8 + j];
            unsigned short h = f2bf(v);
            fh.us[j] = h;
            fl.us[j] = f2bf(v - bf2f(h));
        }
        wtab[(m*4+0)*64 + lane] = make_uint4(fh.w[0], fh.w[1], fh.w[2], fh.w[3]);
        wtab[(m*4+1)*64 + lane] = make_uint4(fl.w[0], fl.w[1], fl.w[2], fl.w[3]);

        const float* hr = whh + (gt*24 + u)*24;
        FragAB gh, gl;
        #pragma unroll
        for (int j = 0; j < 8; ++j) {
            const int k = q*8 + j;
            float v = (k < 24) ? hr[k] : ((k == 24) ? wr[32] : 0.f);
            unsigned short h = f2bf(v);
            gh.us[j] = h;
            gl.us[j] = (k < 24) ? f2bf(v - bf2f(h)) : (unsigned short)0;
        }
        wtab[(m*4+2)*64 + lane] = make_uint4(gh.w[0], gh.w[1], gh.w[2], gh.w[3]);
        wtab[(m*4+3)*64 + lane] = make_uint4(gl.w[0], gl.w[1], gl.w[2], gl.w[3]);

        const int uu = 4*m + q;
        btab[m*64 + lane] = make_float4(bih[uu]      + bhh[uu],
                                        bih[24+uu]   + bhh[24+uu],
                                        bih[48+uu]   + bhh[48+uu],
                                        bih[72+uu]   + bhh[72+uu]);
    }
}

// ============ Kernel 1: conv+LIF, time-tiled (8 supersteps x 11 positions) ============
// Block = 256 threads, 16 samples. Per superstep: coalesced x stage -> LDS,
// conv threads (pg<11) do 1 position each -> hv[132][17], LIF threads (all 16 kg)
// advance 2 chains x 4 timesteps with state+timelines in registers. ~25 KB LDS.
__global__ __launch_bounds__(256)
void k_conv_lif(const float* __restrict__ x,
                const float* __restrict__ c1w, const float* __restrict__ c1b,
                const float* __restrict__ b1g, const float* __restrict__ b1b,
                const float* __restrict__ b1m, const float* __restrict__ b1v,
                const float* __restrict__ c2w, const float* __restrict__ c2b,
                const float* __restrict__ b2g, const float* __restrict__ b2b,
                const float* __restrict__ b2m, const float* __restrict__ b2v,
                u64* __restrict__ spk,
                float* __restrict__ avg)
{
    __shared__ float    xs[16][68];      // staged x chunk, 16B-aligned rows, 2-way banks
    __shared__ float    hv[132][17];     // conv2 post-BN relu values for 4 timesteps
    __shared__ unsigned tml[33][16];     // per-chain spike timelines
    __shared__ float    pavg[12][11][17];

    const int tid  = threadIdx.x;
    const int sm   = tid & 15;
    const int pg   = tid >> 4;           // conv: position in superstep; LIF: chain group
    const int bidx = blockIdx.x * 16 + sm;

    // fold conv1 bias + bn1 (identical op order to prior rounds)
    float w1f[6][5], c1f[6];
    #pragma unroll
    for (int c = 0; c < 6; ++c) {
        float s = b1g[c] / sqrtf(b1v[c] + 1e-5f);
        #pragma unroll
        for (int j = 0; j < 5; ++j) w1f[c][j] = c1w[c*5+j] * s;
        c1f[c] = (c1b[c] - b1m[c]) * s + b1b[c];
    }
    float s2v[12], t2v[12], sum12[12];
    #pragma unroll
    for (int c = 0; c < 12; ++c) {
        float s = b2g[c] / sqrtf(b2v[c] + 1e-5f);
        s2v[c] = s;
        t2v[c] = (c2b[c] - b2m[c]) * s + b2b[c];
        sum12[c] = 0.f;
    }

    // LIF state (chains kka, kkb; kg==15 also chain 32)
    const int kka = 2*pg, kkb = 2*pg + 1;
    const bool hc = (pg == 15);
    float m1a=0.f,m2a=0.f,m1b=0.f,m2b=0.f,m1c=0.f,m2c=0.f;
    unsigned ba=0u, bb=0u, bc=0u;

    #pragma unroll 1
    for (int ss = 0; ss < 8; ++ss) {
        // ---- stage x[44ss-4 .. 44ss+60) for this block's 16 samples, coalesced ----
        {
            const int samp = tid >> 4;       // 0..15
            const int ch   = tid & 15;       // float4 chunk
            const int gi   = 44*ss - 4 + 4*ch;
            float4 v;
            if (gi >= 0 && gi <= 356)
                v = *(const float4*)(x + (size_t)(blockIdx.x*16 + samp)*360 + gi);
            else
                v = make_float4(0.f,0.f,0.f,0.f);
            *(float4*)&xs[samp][4*ch] = v;
        }
        __syncthreads();

        // ---- conv: pg<11 computes position p = 11ss+pg -> 12 hv values ----
        if (pg < 11) {
            const int p = 11*ss + pg;
            float xw[9];
            #pragma unroll
            for (int k2 = 0; k2 < 9; ++k2) xw[k2] = xs[sm][4*pg + k2];

            float hA[6], hB[6], hC[6];
            const bool valid = (p > 0);
            #pragma unroll
            for (int c = 0; c < 6; ++c) {
                float aA = c1f[c] + w1f[c][0]*xw[0] + w1f[c][1]*xw[1]
                         + w1f[c][2]*xw[2] + w1f[c][3]*xw[3] + w1f[c][4]*xw[4];
                float aB = c1f[c] + w1f[c][0]*xw[2] + w1f[c][1]*xw[3]
                         + w1f[c][2]*xw[4] + w1f[c][3]*xw[5] + w1f[c][4]*xw[6];
                float aC = c1f[c] + w1f[c][0]*xw[4] + w1f[c][1]*xw[5]
                         + w1f[c][2]*xw[6] + w1f[c][3]*xw[7] + w1f[c][4]*xw[8];
                hA[c] = valid ? fmaxf(aA, 0.f) : 0.f;
                hB[c] = fmaxf(aB, 0.f);
                hC[c] = fmaxf(aC, 0.f);
            }
            #pragma unroll
            for (int c2 = 0; c2 < 12; ++c2) {
                float acc = 0.f;
                #pragma unroll
                for (int c1 = 0; c1 < 6; ++c1) {
                    const float* wp = c2w + c2*18 + c1*3;
                    acc += wp[0]*hA[c1] + wp[1]*hB[c1] + wp[2]*hC[c1];
                }
                float hvv = fmaxf(acc*s2v[c2] + t2v[c2], 0.f);
                sum12[c2] += hvv;
                hv[12*pg + c2][sm] = hvv;
            }
        }
        __syncthreads();

        // ---- LIF: 4 timesteps of this superstep, all 16 chain-groups ----
        #pragma unroll
        for (int tl = 0; tl < 4; ++tl) {
            const int t = 4*ss + tl;
            const float va = hv[33*tl + kka][sm];
            const float vb = hv[33*tl + kkb][sm];
            { m1a = 0.95f*m1a + va; float s1 = (m1a>0.5f)?1.f:0.f; m1a *= (1.f-s1);
              float v2 = 0.9f*m2a + s1; bool s2 = (v2>0.6f); m2a = s2?0.f:v2;
              if (s2) ba |= (1u<<t); }
            { m1b = 0.95f*m1b + vb; float s1 = (m1b>0.5f)?1.f:0.f; m1b *= (1.f-s1);
              float v2 = 0.9f*m2b + s1; bool s2 = (v2>0.6f); m2b = s2?0.f:v2;
              if (s2) bb |= (1u<<t); }
            if (hc) {
              const float vc = hv[33*tl + 32][sm];
              m1c = 0.95f*m1c + vc; float s1 = (m1c>0.5f)?1.f:0.f; m1c *= (1.f-s1);
              float v2 = 0.9f*m2c + s1; bool s2 = (v2>0.6f); m2c = s2?0.f:v2;
              if (s2) bc |= (1u<<t); }
        }
        __syncthreads();   // hv reads done before next superstep overwrites
    }

    // ---- tail positions 88 (pg==0) and 89 (pg==1): avg only ----
    if (pg < 2) {
        const int p = 88 + pg;
        const int xbase = 4*p - 4;
        float xw[12];
        #pragma unroll
        for (int e = 0; e < 3; ++e) {
            const int gi = xbase + 4*e;
            float4 v;
            if (gi <= 356) v = *(const float4*)(x + (size_t)bidx*360 + gi);
            else           v = make_float4(0.f,0.f,0.f,0.f);
            xw[4*e+0]=v.x; xw[4*e+1]=v.y; xw[4*e+2]=v.z; xw[4*e+3]=v.w;
        }
        float hA[6], hB[6], hC[6];
        #pragma unroll
        for (int c = 0; c < 6; ++c) {
            float aA = c1f[c] + w1f[c][0]*xw[0] + w1f[c][1]*xw[1]
                     + w1f[c][2]*xw[2] + w1f[c][3]*xw[3] + w1f[c][4]*xw[4];
            float aB = c1f[c] + w1f[c][0]*xw[2] + w1f[c][1]*xw[3]
                     + w1f[c][2]*xw[4] + w1f[c][3]*xw[5] + w1f[c][4]*xw[6];
            float aC = c1f[c] + w1f[c][0]*xw[4] + w1f[c][1]*xw[5]
                     + w1f[c][2]*xw[6] + w1f[c][3]*xw[7] + w1f[c][4]*xw[8];
            hA[c] = fmaxf(aA, 0.f);
            hB[c] = fmaxf(aB, 0.f);
            hC[c] = fmaxf(aC, 0.f);
        }
        #pragma unroll
        for (int c2 = 0; c2 < 12; ++c2) {
            float acc = 0.f;
            #pragma unroll
            for (int c1 = 0; c1 < 6; ++c1) {
                const float* wp = c2w + c2*18 + c1*3;
                acc += wp[0]*hA[c1] + wp[1]*hB[c1] + wp[2]*hC[c1];
            }
            sum12[c2] += fmaxf(acc*s2v[c2] + t2v[c2], 0.f);
        }
    }

    // ---- publish timelines + avg partials ----
    tml[kka][sm] = ba;
    tml[kkb][sm] = bb;
    if (hc) tml[32][sm] = bc;
    if (pg < 11) {
        #pragma unroll
        for (int c2 = 0; c2 < 12; ++c2) pavg[c2][pg][sm] = sum12[c2];
    }
    __syncthreads();

    // ---- transpose timelines -> packed spike words; reduce avg ----
    {
        const int tg = pg;               // t = 2tg, 2tg+1
        u64 w0 = 0ull, w1 = 0ull;
        #pragma unroll
        for (int kk = 0; kk < 33; ++kk) {
            const unsigned r = tml[kk][sm];
            w0 |= (u64)((r >> (2*tg  )) & 1u) << kk;
            w1 |= (u64)((r >> (2*tg+1)) & 1u) << kk;
        }
        spk[(size_t)(2*tg  )*NB + bidx] = w0;
        spk[(size_t)(2*tg+1)*NB + bidx] = w1;
    }
    if (tid < 192) {
        const int c2 = tid >> 4;
        float s = 0.f;
        #pragma unroll
        for (int g = 0; g < 11; ++g) s += pavg[c2][g][sm];
        avg[(size_t)c2*NB + bidx] = s / 90.0f;
    }
}

// ============ Kernel 2: MFMA LSTM (split-bf16, preloaded fragments) + heads ============
__global__ __launch_bounds__(64)
void k_lstm_mfma(const u64* __restrict__ spk,
                 const float* __restrict__ avg,
                 const uint4* __restrict__ wtab, const float4* __restrict__ btab,
                 const float* __restrict__ rw1, const float* __restrict__ rb1,
                 const float* __restrict__ rw2, const float* __restrict__ rb2,
                 const float* __restrict__ fw,  const float* __restrict__ fb,
                 const float* __restrict__ cw1, const float* __restrict__ cb1,
                 const float* __restrict__ cw2, const float* __restrict__ cb2,
                 float* __restrict__ out)
{
    __shared__ unsigned short hx[16][64];  // [n][0..23]=h_hi, [32..55]=h_lo, rest 0
    __shared__ float hf[16][24];

    const int lane = threadIdx.x & 63;
    const int q    = lane >> 4;
    const int n16  = lane & 15;
    const int sample = blockIdx.x * 16 + n16;

    {   // zero hx
        unsigned* zp = (unsigned*)&hx[0][0];
        #pragma unroll
        for (int i = 0; i < 8; ++i) zp[lane + 64*i] = 0u;
    }

    // ---- coalesced fragment load (prebuilt by k_setup) ----
    short8 WihHi[6], WihLo[6], WhhHi[6], WhhLo[6];
    float4 bias[6];
    #pragma unroll
    for (int m = 0; m < 6; ++m) {
        WU a0, a1, a2, a3;
        a0.u4 = wtab[(m*4+0)*64 + lane];
        a1.u4 = wtab[(m*4+1)*64 + lane];
        a2.u4 = wtab[(m*4+2)*64 + lane];
        a3.u4 = wtab[(m*4+3)*64 + lane];
        WihHi[m] = a0.v; WihLo[m] = a1.v; WhhHi[m] = a2.v; WhhLo[m] = a3.v;
        bias[m] = btab[m*64 + lane];
    }

    float cst[6], hreg[6];
    #pragma unroll
    for (int m = 0; m < 6; ++m) { cst[m] = 0.f; hreg[m] = 0.f; }

    const u64* sp = spk + sample;
    u64 wcur = sp[0];
    const int q8 = q * 8;

    __asm__ volatile("s_waitcnt lgkmcnt(0)" ::: "memory");

    #pragma unroll 1
    for (int t = 0; t < 32; ++t) {
        FragAB bhHi, bhLo;
        bhHi.v = *reinterpret_cast<const short8*>(&hx[n16][q8]);
        bhLo.v = *reinterpret_cast<const short8*>(&hx[n16][32 + q8]);

        const unsigned lo32 = (unsigned)wcur;
        const unsigned hi32 = (unsigned)(wcur >> 32);
        // patch B slot k=24 (q==3, j==0) with spike bit 32 (exact bf16 0/1)
        if (q == 3) bhHi.us[0] = (hi32 & 1u) ? (unsigned short)0x3F80 : (unsigned short)0;

        FragAB bs0;
        {
            const unsigned byt = (lo32 >> q8) & 0xFFu;
            #pragma unroll
            for (int p = 0; p < 4; ++p) {
                unsigned e0 = (byt >> (2*p)) & 1u;
                unsigned e1 = (byt >> (2*p+1)) & 1u;
                bs0.w[p] = (e0 ? 0x3F80u : 0u) | (e1 ? 0x3F800000u : 0u);
            }
        }

        u64 wnext = 0;
        if (t < 31) wnext = sp[(size_t)(t+1)*NB];

        f32x4 acc[6];
        #pragma unroll
        for (int m = 0; m < 6; ++m) {
            f32x4 a; a[0]=bias[m].x; a[1]=bias[m].y; a[2]=bias[m].z; a[3]=bias[m].w;
            a = __builtin_amdgcn_mfma_f32_16x16x32_bf16(WihHi[m], bs0.v,  a, 0, 0, 0);
            a = __builtin_amdgcn_mfma_f32_16x16x32_bf16(WihLo[m], bs0.v,  a, 0, 0, 0);
            a = __builtin_amdgcn_mfma_f32_16x16x32_bf16(WhhHi[m], bhHi.v, a, 0, 0, 0);
            a = __builtin_amdgcn_mfma_f32_16x16x32_bf16(WhhLo[m], bhHi.v, a, 0, 0, 0);
            a = __builtin_amdgcn_mfma_f32_16x16x32_bf16(WhhHi[m], bhLo.v, a, 0, 0, 0);
            acc[m] = a;
        }

        #pragma unroll
        for (int m = 0; m < 6; ++m) {
            float ii = sigf(acc[m][0]);
            float ff = sigf(acc[m][1]);
            float gg = tanh_fast(acc[m][2]);
            float oo = sigf(acc[m][3]);
            float cn = ff*cst[m] + ii*gg;
            cst[m] = cn;
            float h = oo * tanh_fast(cn);
            hreg[m] = h;
            unsigned short hh = f2bf(h);
            unsigned short hl = f2bf(h - bf2f(hh));
            hx[n16][4*m + q]      = hh;
            hx[n16][32 + 4*m + q] = hl;
        }
        __asm__ volatile("s_waitcnt lgkmcnt(0)" ::: "memory");
        wcur = wnext;
    }

    #pragma unroll
    for (int m = 0; m < 6; ++m) hf[n16][4*m + q] = hreg[m];
    __asm__ volatile("s_waitcnt lgkmcnt(0)" ::: "memory");

    if (lane < 16) {
        const int sm = lane;
        const int bidx = blockIdx.x * 16 + sm;
        float h[24];
        #pragma unroll
        for (int u2 = 0; u2 < 24; ++u2) h[u2] = hf[sm][u2];
        float av[12];
        #pragma unroll
        for (int cc = 0; cc < 12; ++cc) av[cc] = avg[(size_t)cc*NB + bidx];

        float f1[12];
        #pragma unroll
        for (int r = 0; r < 12; ++r) {
            float a = rb1[r];
            #pragma unroll
            for (int u2 = 0; u2 < 24; ++u2) a += rw1[r*36+u2]*h[u2];
            #pragma unroll
            for (int cc = 0; cc < 12; ++cc) a += rw1[r*36+24+cc]*av[cc];
            f1[r] = fmaxf(a, 0.f);
        }
        float z0 = rb2[0], z1 = rb2[1];
        #pragma unroll
        for (int r = 0; r < 12; ++r) { z0 += rw2[r]*f1[r]; z1 += rw2[12+r]*f1[r]; }
        float mz = fmaxf(z0, z1);
        float e0 = __expf(z0 - mz), e1 = __expf(z1 - mz);
        float inv = 1.0f/(e0 + e1);
        float r0 = 0.7f*e0*inv, r1 = 0.3f*e1*inv;
        float alpha = r0/(r0 + r1);

        float ha[24], sa[12];
        #pragma unroll
        for (int u2 = 0; u2 < 24; ++u2) ha[u2] = h[u2]*alpha;
        #pragma unroll
        for (int cc = 0; cc < 12; ++cc) sa[cc] = av[cc]*(1.f - alpha);

        float fu[24];
        #pragma unroll
        for (int r = 0; r < 24; ++r) {
            float a = fb[r];
            #pragma unroll
            for (int u2 = 0; u2 < 24; ++u2) a += fw[r*36+u2]*ha[u2];
            #pragma unroll
            for (int cc = 0; cc < 12; ++cc) a += fw[r*36+24+cc]*sa[cc];
            fu[r] = fmaxf(a, 0.f);
        }
        float c1o[12];
        #pragma unroll
        for (int r = 0; r < 12; ++r) {
            float a = cb1[r];
            #pragma unroll
            for (int u2 = 0; u2 < 24; ++u2) a += cw1[r*24+u2]*fu[u2];
            c1o[r] = fmaxf(a, 0.f);
        }
        #pragma unroll
        for (int o = 0; o < 5; ++o) {
            float a = cb2[o];
            #pragma unroll
            for (int r = 0; r < 12; ++r) a += cw2[o*12+r]*c1o[r];
            out[(size_t)bidx*5 + o] = a;
        }
    }
}

extern "C" void kernel_launch(void* const* d_in, const int* in_sizes, int n_in,
                              void* d_out, int out_size, void* d_ws, size_t ws_size,
                              hipStream_t stream) {
    const float* x    = (const float*)d_in[0];
    const float* c1w  = (const float*)d_in[1];
    const float* c1b  = (const float*)d_in[2];
    const float* b1g  = (const float*)d_in[3];
    const float* b1b  = (const float*)d_in[4];
    const float* b1m  = (const float*)d_in[5];
    const float* b1v  = (const float*)d_in[6];
    const float* c2w  = (const float*)d_in[7];
    const float* c2b  = (const float*)d_in[8];
    const float* b2g  = (const float*)d_in[9];
    const float* b2b  = (const float*)d_in[10];
    const float* b2m  = (const float*)d_in[11];
    const float* b2v  = (const float*)d_in[12];
    const float* wih  = (const float*)d_in[13];
    const float* whh  = (const float*)d_in[14];
    const float* bih  = (const float*)d_in[15];
    const float* bhh  = (const float*)d_in[16];
    const float* rw1  = (const float*)d_in[17];
    const float* rb1  = (const float*)d_in[18];
    const float* rw2  = (const float*)d_in[19];
    const float* rb2  = (const float*)d_in[20];
    const float* fw   = (const float*)d_in[21];
    const float* fb   = (const float*)d_in[22];
    const float* cw1  = (const float*)d_in[23];
    const float* cb1  = (const float*)d_in[24];
    const float* cw2  = (const float*)d_in[25];
    const float* cb2  = (const float*)d_in[26];
    float* out = (float*)d_out;

    char* ws = (char*)d_ws;
    u64*    spk  = (u64*)ws;                                    // 16.78 MB
    float*  avg  = (float*)(ws + (size_t)32*NB*8);              // 3.15 MB
    uint4*  wtab = (uint4*)(ws + (size_t)32*NB*8 + (size_t)12*NB*4);        // 24.6 KB
    float4* btab = (float4*)(ws + (size_t)32*NB*8 + (size_t)12*NB*4 + 24*64*16);

    k_setup<<<dim3(1), dim3(64), 0, stream>>>(wih, whh, bih, bhh, wtab, btab);
    k_conv_lif<<<dim3(NB/16), dim3(256), 0, stream>>>(x, c1w, c1b, b1g, b1b, b1m, b1v,
                                                      c2w, c2b, b2g, b2b, b2m, b2v, spk, avg);
    k_lstm_mfma<<<dim3(NB/16), dim3(64), 0, stream>>>(spk, avg, wtab, btab,
                                                      rw1, rb1, rw2, rb2, fw, fb,
                                                      cw1, cb1, cw2, cb2, out);
}